// Round 3
// baseline (265.090 us; speedup 1.0000x reference)
//
#include <hip/hip_runtime.h>
#include <math.h>

#define TT 1024   // tokens
#define HH 1024   // hidden
#define MM 512    // moe intermediate
#define NE 16     // routed experts (blockIdx.z == NE -> shared expert)
// TOP_K = 2, SCALE = 2.5, NORM_TOPK = true

typedef _Float16 f16;
typedef _Float16 f16x8 __attribute__((ext_vector_type(8)));
typedef float f32x4 __attribute__((ext_vector_type(4)));

// LDS rows padded to 72 f16 (144 B): bank_group = (36*row + col/2) % 32
// = 4*(row&7) + col/2  -> for 64 b128 ops with 64 distinct rows (or 16 rows x 4
// k-groups), 8 groups x 8 lanes = the 8-cycle minimum. Conflict-free, no swizzle.
#define LPAD 72

// ---------------- router: scores, top-2, per-expert dispatch lists ----------------
__global__ __launch_bounds__(256) void router_k(
    const float* __restrict__ x, const float* __restrict__ gate_w,
    int* __restrict__ counts, int* __restrict__ token_list, float* __restrict__ weight_list)
{
    const int wave = threadIdx.x >> 6;
    const int lane = threadIdx.x & 63;
    const int t = (blockIdx.x << 2) + wave;
    const float* xr = x + (size_t)t * HH;
    float xv[16];
#pragma unroll
    for (int i = 0; i < 16; ++i) xv[i] = xr[lane + (i << 6)];
    float sc[NE];
#pragma unroll
    for (int e = 0; e < NE; ++e) {
        const float* gr = gate_w + e * HH;
        float acc = 0.f;
#pragma unroll
        for (int i = 0; i < 16; ++i) acc = fmaf(xv[i], gr[lane + (i << 6)], acc);
#pragma unroll
        for (int off = 32; off > 0; off >>= 1) acc += __shfl_down(acc, off, 64);
        sc[e] = acc;   // valid on lane 0
    }
    if (lane == 0) {
        // sigmoid monotonic -> top-2 on logits; first-index-wins on ties
        float l1 = -1e30f, l2 = -1e30f; int i1 = 0, i2 = 0;
#pragma unroll
        for (int e = 0; e < NE; ++e) {
            float v = sc[e];
            if (v > l1) { l2 = l1; i2 = i1; l1 = v; i1 = e; }
            else if (v > l2) { l2 = v; i2 = e; }
        }
        float w1 = 1.f / (1.f + __expf(-l1));
        float w2 = 1.f / (1.f + __expf(-l2));
        const float inv = 2.5f / (w1 + w2 + 1e-20f);
        w1 *= inv; w2 *= inv;
        int s1 = atomicAdd(&counts[i1], 1);
        token_list[i1 * TT + s1] = t;
        weight_list[i1 * TT + s1] = w1;
        int s2 = atomicAdd(&counts[i2], 1);
        token_list[i2 * TT + s2] = t;
        weight_list[i2 * TT + s2] = w2;
    }
}

__global__ void prefix_k(const int* __restrict__ counts, int* __restrict__ offs)
{
    if (threadIdx.x == 0 && blockIdx.x == 0) {
        int acc = 0;
#pragma unroll
        for (int e = 0; e < NE; ++e) { offs[e] = acc; acc += counts[e]; }
        offs[NE] = acc;
    }
}

// ---------------- fused gate/up: rinter[slot] = f16( silu(x@Wg) * (x@Wu) ) ----------------
// BM=128, BN=64, BK=64, 512 threads (8 waves, 4m x 2n), register-prefetch pipeline.
__global__ __launch_bounds__(512) void gu_k(
    const float* __restrict__ x,
    const float* __restrict__ w_gate, const float* __restrict__ w_up,
    const float* __restrict__ ws_gate, const float* __restrict__ ws_up,
    const int* __restrict__ counts, const int* __restrict__ offs,
    const int* __restrict__ token_list, f16* __restrict__ rinter)
{
    const int e = blockIdx.z;
    int cnt, slot0;
    const float *wgp, *wup;
    if (e < NE) {
        cnt = counts[e]; slot0 = offs[e];
        wgp = w_gate + (size_t)e * HH * MM;
        wup = w_up   + (size_t)e * HH * MM;
    } else {
        cnt = TT; slot0 = 2 * TT;          // shared expert: identity routing
        wgp = ws_gate; wup = ws_up;
    }
    const int r0 = blockIdx.x << 7;
    if (r0 >= cnt) return;
    const int n0 = blockIdx.y << 6;

    __shared__ f16 As[128][LPAD];
    __shared__ f16 Bgs[64][LPAD];
    __shared__ f16 Bus[64][LPAD];
    __shared__ int toks[128];

    const int tid = threadIdx.x;
    if (tid < 128) {
        int i = r0 + tid; if (i >= cnt) i = cnt - 1;
        toks[tid] = (e < NE) ? token_list[e * TT + i] : i;
    }
    __syncthreads();

    // staging: A -> thread owns (row ar, 16 k at akb); B -> (row bn, 16 k at bkb),
    // waves 0-3 stage Bg, waves 4-7 stage Bu. B global reads are 64 consecutive
    // dwords per row across a wave (256B segments, coalesced).
    const int ar  = tid & 127;
    const int akb = (tid >> 7) << 4;
    const int bn  = tid & 63;
    const int bw  = tid >> 6;
    const int bkb = (bw & 3) << 4;
    const float* bsrc = (bw < 4) ? wgp : wup;
    f16* brow_lds = (bw < 4) ? &Bgs[bn][0] : &Bus[bn][0];

    const int w = tid >> 6, l = tid & 63;
    const int wm = (w >> 1) << 5;      // 0,32,64,96
    const int wn = (w & 1) << 5;       // 0,32
    const int lm = l & 15, lg = l >> 4;

    const float* arow = x + (size_t)toks[ar] * HH;

    f32x4 accg[2][2] = {}, accu[2][2] = {};
    float pa[16], pb[16];

    // prefetch tile 0
#pragma unroll
    for (int u = 0; u < 4; ++u) {
        float4 v = *(const float4*)(arow + akb + (u << 2));
        pa[4*u] = v.x; pa[4*u+1] = v.y; pa[4*u+2] = v.z; pa[4*u+3] = v.w;
    }
#pragma unroll
    for (int i = 0; i < 16; ++i) pb[i] = bsrc[(size_t)(bkb + i) * MM + n0 + bn];
    {
        f16x8 h0, h1, g0, g1;
#pragma unroll
        for (int j = 0; j < 8; ++j) {
            h0[j] = (f16)pa[j]; h1[j] = (f16)pa[8+j];
            g0[j] = (f16)pb[j]; g1[j] = (f16)pb[8+j];
        }
        *(f16x8*)&As[ar][akb] = h0; *(f16x8*)&As[ar][akb + 8] = h1;
        *(f16x8*)(brow_lds + bkb) = g0; *(f16x8*)(brow_lds + bkb + 8) = g1;
    }
    __syncthreads();

    for (int kt = 0; kt < HH / 64; ++kt) {
        const bool more = (kt + 1 < HH / 64);
        if (more) {
            const int k0 = (kt + 1) << 6;
#pragma unroll
            for (int u = 0; u < 4; ++u) {
                float4 v = *(const float4*)(arow + k0 + akb + (u << 2));
                pa[4*u] = v.x; pa[4*u+1] = v.y; pa[4*u+2] = v.z; pa[4*u+3] = v.w;
            }
#pragma unroll
            for (int i = 0; i < 16; ++i) pb[i] = bsrc[(size_t)(k0 + bkb + i) * MM + n0 + bn];
        }
        // compute current tile (hides the prefetch latency)
#pragma unroll
        for (int h = 0; h < 2; ++h) {
            const int kf = (h << 5) + (lg << 3);
            f16x8 af[2], bgf[2], buf2[2];
#pragma unroll
            for (int f = 0; f < 2; ++f) {
                af[f]   = *(const f16x8*)&As[wm + (f << 4) + lm][kf];
                bgf[f]  = *(const f16x8*)&Bgs[wn + (f << 4) + lm][kf];
                buf2[f] = *(const f16x8*)&Bus[wn + (f << 4) + lm][kf];
            }
#pragma unroll
            for (int fi = 0; fi < 2; ++fi)
#pragma unroll
                for (int fj = 0; fj < 2; ++fj) {
                    accg[fi][fj] = __builtin_amdgcn_mfma_f32_16x16x32_f16(af[fi], bgf[fj], accg[fi][fj], 0, 0, 0);
                    accu[fi][fj] = __builtin_amdgcn_mfma_f32_16x16x32_f16(af[fi], buf2[fj], accu[fi][fj], 0, 0, 0);
                }
        }
        if (more) {
            __syncthreads();   // all reads of this buffer done
            f16x8 h0, h1, g0, g1;
#pragma unroll
            for (int j = 0; j < 8; ++j) {
                h0[j] = (f16)pa[j]; h1[j] = (f16)pa[8+j];
                g0[j] = (f16)pb[j]; g1[j] = (f16)pb[8+j];
            }
            *(f16x8*)&As[ar][akb] = h0; *(f16x8*)&As[ar][akb + 8] = h1;
            *(f16x8*)(brow_lds + bkb) = g0; *(f16x8*)(brow_lds + bkb + 8) = g1;
            __syncthreads();   // writes visible
        }
    }
    // epilogue: silu(g)*u -> f16; C/D: col=lane&15, row=(lane>>4)*4+reg
#pragma unroll
    for (int fi = 0; fi < 2; ++fi)
#pragma unroll
        for (int rr = 0; rr < 4; ++rr) {
            const int m = wm + (fi << 4) + (lg << 2) + rr;
            if (r0 + m < cnt) {
                f16* orow = rinter + (size_t)(slot0 + r0 + m) * MM + n0;
#pragma unroll
                for (int fj = 0; fj < 2; ++fj) {
                    float g = accg[fi][fj][rr], u = accu[fi][fj][rr];
                    float s = g / (1.f + __expf(-g));
                    orow[wn + (fj << 4) + lm] = (f16)(s * u);
                }
            }
        }
}

// ---------------- down: out[token] += weight * (rinter @ Wd)  (shared: weight=1) --------
__global__ __launch_bounds__(512) void down_k(
    const f16* __restrict__ rinter,
    const float* __restrict__ w_down, const float* __restrict__ ws_down,
    const int* __restrict__ counts, const int* __restrict__ offs,
    const int* __restrict__ token_list, const float* __restrict__ weight_list,
    float* __restrict__ out)
{
    const int e = blockIdx.z;
    int cnt, slot0; const float* wdp;
    if (e < NE) { cnt = counts[e]; slot0 = offs[e]; wdp = w_down + (size_t)e * MM * HH; }
    else        { cnt = TT; slot0 = 2 * TT; wdp = ws_down; }
    const int r0 = blockIdx.x << 7;
    if (r0 >= cnt) return;
    const int n0 = blockIdx.y << 6;   // of HH

    __shared__ f16 As[128][LPAD];
    __shared__ f16 Bs[64][LPAD];

    const int tid = threadIdx.x;
    const int ar  = tid & 127;
    const int akb = (tid >> 7) << 4;
    const int bn  = tid & 63;
    const int bkb = (tid >> 6) << 3;   // 8 k per thread

    const int w = tid >> 6, l = tid & 63;
    const int wm = (w >> 1) << 5;
    const int wn = (w & 1) << 5;
    const int lm = l & 15, lg = l >> 4;

    int ari = r0 + ar; if (ari >= cnt) ari = cnt - 1;
    const f16* arow = rinter + (size_t)(slot0 + ari) * MM;

    f32x4 acc[2][2] = {};
    f16x8 pa0, pa1; float pb[8];

    pa0 = *(const f16x8*)(arow + akb);
    pa1 = *(const f16x8*)(arow + akb + 8);
#pragma unroll
    for (int i = 0; i < 8; ++i) pb[i] = wdp[(size_t)(bkb + i) * HH + n0 + bn];
    {
        f16x8 g0;
#pragma unroll
        for (int j = 0; j < 8; ++j) g0[j] = (f16)pb[j];
        *(f16x8*)&As[ar][akb] = pa0; *(f16x8*)&As[ar][akb + 8] = pa1;
        *(f16x8*)&Bs[bn][bkb] = g0;
    }
    __syncthreads();

    for (int kt = 0; kt < MM / 64; ++kt) {
        const bool more = (kt + 1 < MM / 64);
        if (more) {
            const int k0 = (kt + 1) << 6;
            pa0 = *(const f16x8*)(arow + k0 + akb);
            pa1 = *(const f16x8*)(arow + k0 + akb + 8);
#pragma unroll
            for (int i = 0; i < 8; ++i) pb[i] = wdp[(size_t)(k0 + bkb + i) * HH + n0 + bn];
        }
#pragma unroll
        for (int h = 0; h < 2; ++h) {
            const int kf = (h << 5) + (lg << 3);
            f16x8 af[2], bf[2];
#pragma unroll
            for (int f = 0; f < 2; ++f) {
                af[f] = *(const f16x8*)&As[wm + (f << 4) + lm][kf];
                bf[f] = *(const f16x8*)&Bs[wn + (f << 4) + lm][kf];
            }
#pragma unroll
            for (int fi = 0; fi < 2; ++fi)
#pragma unroll
                for (int fj = 0; fj < 2; ++fj)
                    acc[fi][fj] = __builtin_amdgcn_mfma_f32_16x16x32_f16(af[fi], bf[fj], acc[fi][fj], 0, 0, 0);
        }
        if (more) {
            __syncthreads();
            f16x8 g0;
#pragma unroll
            for (int j = 0; j < 8; ++j) g0[j] = (f16)pb[j];
            *(f16x8*)&As[ar][akb] = pa0; *(f16x8*)&As[ar][akb + 8] = pa1;
            *(f16x8*)&Bs[bn][bkb] = g0;
            __syncthreads();
        }
    }
#pragma unroll
    for (int fi = 0; fi < 2; ++fi)
#pragma unroll
        for (int rr = 0; rr < 4; ++rr) {
            const int m = wm + (fi << 4) + (lg << 2) + rr;
            const int row = r0 + m;
            if (row < cnt) {
                int t; float wt;
                if (e < NE) { t = token_list[e * TT + row]; wt = weight_list[e * TT + row]; }
                else        { t = row; wt = 1.f; }
                float* orow = out + (size_t)t * HH + n0;
#pragma unroll
                for (int fj = 0; fj < 2; ++fj)
                    atomicAdd(&orow[wn + (fj << 4) + lm], wt * acc[fi][fj][rr]);
            }
        }
}

extern "C" void kernel_launch(void* const* d_in, const int* in_sizes, int n_in,
                              void* d_out, int out_size, void* d_ws, size_t ws_size,
                              hipStream_t stream)
{
    const float* x       = (const float*)d_in[0];
    const float* gate_w  = (const float*)d_in[1];
    const float* w_gate  = (const float*)d_in[2];
    const float* w_up    = (const float*)d_in[3];
    const float* w_down  = (const float*)d_in[4];
    const float* ws_gate = (const float*)d_in[5];
    const float* ws_up   = (const float*)d_in[6];
    const float* ws_down = (const float*)d_in[7];
    float* out = (float*)d_out;

    // workspace: counts[16] | offs[17] | pad to 64 ints | token_list[16*1024] |
    // weight_list[16*1024] | rinter f16 [3072][512]
    int* counts = (int*)d_ws;
    int* offs = counts + 16;
    int* token_list = counts + 64;
    float* weight_list = (float*)(counts + 64 + NE * TT);
    f16* rinter = (f16*)(counts + 64 + 2 * NE * TT);

    hipMemsetAsync(counts, 0, 64, stream);
    hipMemsetAsync(out, 0, (size_t)TT * HH * sizeof(float), stream);
    router_k<<<dim3(TT / 4), 256, 0, stream>>>(x, gate_w, counts, token_list, weight_list);
    prefix_k<<<1, 64, 0, stream>>>(counts, offs);
    gu_k<<<dim3(8, MM / 64, NE + 1), 512, 0, stream>>>(
        x, w_gate, w_up, ws_gate, ws_up, counts, offs, token_list, rinter);
    down_k<<<dim3(8, HH / 64, NE + 1), 512, 0, stream>>>(
        rinter, w_down, ws_down, counts, offs, token_list, weight_list, out);
}

// Round 4
// 133.695 us; speedup vs baseline: 1.9828x; 1.9828x over previous
//
#include <hip/hip_runtime.h>
#include <math.h>

#define TT 1024   // tokens
#define HH 1024   // hidden
#define MM 512    // moe intermediate
#define NE 16     // routed experts (blockIdx.z == NE -> shared expert)
// TOP_K = 2, SCALE = 2.5, NORM_TOPK = true

typedef _Float16 f16;
typedef _Float16 f16x8 __attribute__((ext_vector_type(8)));
typedef float f32x4 __attribute__((ext_vector_type(4)));

// LDS rows padded to 72 f16 (144 B). For ds_*_b128: bank group = 4*(row&7)+k/2
// -> 8 groups x 8 lanes = the 8-cycle wave64 b128 structural minimum.
#define LPAD 72

// ---------------- router ----------------
__global__ __launch_bounds__(256) void router_k(
    const float* __restrict__ x, const float* __restrict__ gate_w,
    int* __restrict__ counts, int* __restrict__ token_list, float* __restrict__ weight_list)
{
    const int wave = threadIdx.x >> 6;
    const int lane = threadIdx.x & 63;
    const int t = (blockIdx.x << 2) + wave;
    const float* xr = x + (size_t)t * HH;
    float xv[16];
#pragma unroll
    for (int i = 0; i < 16; ++i) xv[i] = xr[lane + (i << 6)];
    float sc[NE];
#pragma unroll
    for (int e = 0; e < NE; ++e) {
        const float* gr = gate_w + e * HH;
        float acc = 0.f;
#pragma unroll
        for (int i = 0; i < 16; ++i) acc = fmaf(xv[i], gr[lane + (i << 6)], acc);
#pragma unroll
        for (int off = 32; off > 0; off >>= 1) acc += __shfl_down(acc, off, 64);
        sc[e] = acc;   // valid on lane 0
    }
    if (lane == 0) {
        float l1 = -1e30f, l2 = -1e30f; int i1 = 0, i2 = 0;
#pragma unroll
        for (int e = 0; e < NE; ++e) {
            float v = sc[e];
            if (v > l1) { l2 = l1; i2 = i1; l1 = v; i1 = e; }
            else if (v > l2) { l2 = v; i2 = e; }
        }
        float w1 = 1.f / (1.f + __expf(-l1));
        float w2 = 1.f / (1.f + __expf(-l2));
        const float inv = 2.5f / (w1 + w2 + 1e-20f);
        w1 *= inv; w2 *= inv;
        int s1 = atomicAdd(&counts[i1], 1);
        token_list[i1 * TT + s1] = t;
        weight_list[i1 * TT + s1] = w1;
        int s2 = atomicAdd(&counts[i2], 1);
        token_list[i2 * TT + s2] = t;
        weight_list[i2 * TT + s2] = w2;
    }
}

__global__ void prefix_k(const int* __restrict__ counts, int* __restrict__ offs)
{
    if (threadIdx.x == 0 && blockIdx.x == 0) {
        int acc = 0;
#pragma unroll
        for (int e = 0; e < NE; ++e) { offs[e] = acc; acc += counts[e]; }
        offs[NE] = acc;
    }
}

// ---------------- fused gate/up: rinter[slot] = f16( silu(x@Wg) * (x@Wu) ) ----------------
// grid = (n_tiles, row_tiles, experts+1)  -> n fastest => active blocks spread over XCDs.
// BM=64, BN=64, BK=64, 256 threads (4 waves, 2m x 2n), register-prefetch pipeline.
__global__ __launch_bounds__(256) void gu_k(
    const float* __restrict__ x,
    const float* __restrict__ w_gate, const float* __restrict__ w_up,
    const float* __restrict__ ws_gate, const float* __restrict__ ws_up,
    const int* __restrict__ counts, const int* __restrict__ offs,
    const int* __restrict__ token_list, f16* __restrict__ rinter)
{
    const int e = blockIdx.z;
    int cnt, slot0;
    const float *wgp, *wup;
    if (e < NE) {
        cnt = counts[e]; slot0 = offs[e];
        wgp = w_gate + (size_t)e * HH * MM;
        wup = w_up   + (size_t)e * HH * MM;
    } else {
        cnt = TT; slot0 = 2 * TT;          // shared expert: identity routing
        wgp = ws_gate; wup = ws_up;
    }
    const int r0 = blockIdx.y << 6;
    if (r0 >= cnt) return;
    const int n0 = blockIdx.x << 6;

    __shared__ f16 As[64][LPAD];
    __shared__ f16 Bgs[64][LPAD];
    __shared__ f16 Bus[64][LPAD];
    __shared__ int toks[64];

    const int tid = threadIdx.x;
    if (tid < 64) {
        int i = r0 + tid; if (i >= cnt) i = cnt - 1;
        toks[tid] = (e < NE) ? token_list[e * TT + i] : i;
    }
    __syncthreads();

    // staging: thread owns row (tid&63), 16-k chunk ((tid>>6)*16) of each tile
    const int sr  = tid & 63;
    const int skb = (tid >> 6) << 4;

    const int w = tid >> 6, l = tid & 63;
    const int wm = (w >> 1) << 5, wn = (w & 1) << 5;
    const int lm = l & 15, lg = l >> 4;

    const float* arow = x + (size_t)toks[sr] * HH;

    f32x4 accg[2][2] = {}, accu[2][2] = {};
    float pa[16], pg[16], pu[16];

    // prefetch tile 0
#pragma unroll
    for (int u = 0; u < 4; ++u) {
        float4 v = *(const float4*)(arow + skb + (u << 2));
        pa[4*u] = v.x; pa[4*u+1] = v.y; pa[4*u+2] = v.z; pa[4*u+3] = v.w;
    }
#pragma unroll
    for (int i = 0; i < 16; ++i) {
        pg[i] = wgp[(size_t)(skb + i) * MM + n0 + sr];
        pu[i] = wup[(size_t)(skb + i) * MM + n0 + sr];
    }
    {
        f16x8 a0, a1, g0, g1, u0, u1;
#pragma unroll
        for (int j = 0; j < 8; ++j) {
            a0[j] = (f16)pa[j]; a1[j] = (f16)pa[8+j];
            g0[j] = (f16)pg[j]; g1[j] = (f16)pg[8+j];
            u0[j] = (f16)pu[j]; u1[j] = (f16)pu[8+j];
        }
        *(f16x8*)&As[sr][skb] = a0;  *(f16x8*)&As[sr][skb+8] = a1;
        *(f16x8*)&Bgs[sr][skb] = g0; *(f16x8*)&Bgs[sr][skb+8] = g1;
        *(f16x8*)&Bus[sr][skb] = u0; *(f16x8*)&Bus[sr][skb+8] = u1;
    }
    __syncthreads();

    for (int kt = 0; kt < HH / 64; ++kt) {
        const bool more = (kt + 1 < HH / 64);
        if (more) {
            const int k0 = (kt + 1) << 6;
#pragma unroll
            for (int u = 0; u < 4; ++u) {
                float4 v = *(const float4*)(arow + k0 + skb + (u << 2));
                pa[4*u] = v.x; pa[4*u+1] = v.y; pa[4*u+2] = v.z; pa[4*u+3] = v.w;
            }
#pragma unroll
            for (int i = 0; i < 16; ++i) {
                pg[i] = wgp[(size_t)(k0 + skb + i) * MM + n0 + sr];
                pu[i] = wup[(size_t)(k0 + skb + i) * MM + n0 + sr];
            }
        }
        // compute current tile (prefetch in flight)
#pragma unroll
        for (int h = 0; h < 2; ++h) {
            const int kf = (h << 5) + (lg << 3);
            f16x8 af[2], bgf[2], buf2[2];
#pragma unroll
            for (int f = 0; f < 2; ++f) {
                af[f]   = *(const f16x8*)&As[wm + (f << 4) + lm][kf];
                bgf[f]  = *(const f16x8*)&Bgs[wn + (f << 4) + lm][kf];
                buf2[f] = *(const f16x8*)&Bus[wn + (f << 4) + lm][kf];
            }
#pragma unroll
            for (int fi = 0; fi < 2; ++fi)
#pragma unroll
                for (int fj = 0; fj < 2; ++fj) {
                    accg[fi][fj] = __builtin_amdgcn_mfma_f32_16x16x32_f16(af[fi], bgf[fj], accg[fi][fj], 0, 0, 0);
                    accu[fi][fj] = __builtin_amdgcn_mfma_f32_16x16x32_f16(af[fi], buf2[fj], accu[fi][fj], 0, 0, 0);
                }
        }
        if (more) {
            __syncthreads();
            f16x8 a0, a1, g0, g1, u0, u1;
#pragma unroll
            for (int j = 0; j < 8; ++j) {
                a0[j] = (f16)pa[j]; a1[j] = (f16)pa[8+j];
                g0[j] = (f16)pg[j]; g1[j] = (f16)pg[8+j];
                u0[j] = (f16)pu[j]; u1[j] = (f16)pu[8+j];
            }
            *(f16x8*)&As[sr][skb] = a0;  *(f16x8*)&As[sr][skb+8] = a1;
            *(f16x8*)&Bgs[sr][skb] = g0; *(f16x8*)&Bgs[sr][skb+8] = g1;
            *(f16x8*)&Bus[sr][skb] = u0; *(f16x8*)&Bus[sr][skb+8] = u1;
            __syncthreads();
        }
    }
    // epilogue: silu(g)*u -> f16; C/D: col=lane&15, row=(lane>>4)*4+reg
#pragma unroll
    for (int fi = 0; fi < 2; ++fi)
#pragma unroll
        for (int rr = 0; rr < 4; ++rr) {
            const int m = wm + (fi << 4) + (lg << 2) + rr;
            if (r0 + m < cnt) {
                f16* orow = rinter + (size_t)(slot0 + r0 + m) * MM + n0;
#pragma unroll
                for (int fj = 0; fj < 2; ++fj) {
                    float g = accg[fi][fj][rr], u = accu[fi][fj][rr];
                    float s = g / (1.f + __expf(-g));
                    orow[wn + (fj << 4) + lm] = (f16)(s * u);
                }
            }
        }
}

// ---------------- down: out[token] += weight * (rinter @ Wd)  (shared: weight=1) --------
__global__ __launch_bounds__(256) void down_k(
    const f16* __restrict__ rinter,
    const float* __restrict__ w_down, const float* __restrict__ ws_down,
    const int* __restrict__ counts, const int* __restrict__ offs,
    const int* __restrict__ token_list, const float* __restrict__ weight_list,
    float* __restrict__ out)
{
    const int e = blockIdx.z;
    int cnt, slot0; const float* wdp;
    if (e < NE) { cnt = counts[e]; slot0 = offs[e]; wdp = w_down + (size_t)e * MM * HH; }
    else        { cnt = TT; slot0 = 2 * TT; wdp = ws_down; }
    const int r0 = blockIdx.y << 6;
    if (r0 >= cnt) return;
    const int n0 = blockIdx.x << 6;   // of HH

    __shared__ f16 As[64][LPAD];
    __shared__ f16 Bs[64][LPAD];

    const int tid = threadIdx.x;
    const int sr  = tid & 63;
    const int skb = (tid >> 6) << 4;

    const int w = tid >> 6, l = tid & 63;
    const int wm = (w >> 1) << 5, wn = (w & 1) << 5;
    const int lm = l & 15, lg = l >> 4;

    int ari = r0 + sr; if (ari >= cnt) ari = cnt - 1;
    const f16* arow = rinter + (size_t)(slot0 + ari) * MM;

    f32x4 acc[2][2] = {};
    f16x8 pa0, pa1; float pb[16];

    pa0 = *(const f16x8*)(arow + skb);
    pa1 = *(const f16x8*)(arow + skb + 8);
#pragma unroll
    for (int i = 0; i < 16; ++i) pb[i] = wdp[(size_t)(skb + i) * HH + n0 + sr];
    {
        f16x8 g0, g1;
#pragma unroll
        for (int j = 0; j < 8; ++j) { g0[j] = (f16)pb[j]; g1[j] = (f16)pb[8+j]; }
        *(f16x8*)&As[sr][skb] = pa0; *(f16x8*)&As[sr][skb+8] = pa1;
        *(f16x8*)&Bs[sr][skb] = g0;  *(f16x8*)&Bs[sr][skb+8] = g1;
    }
    __syncthreads();

    for (int kt = 0; kt < MM / 64; ++kt) {
        const bool more = (kt + 1 < MM / 64);
        if (more) {
            const int k0 = (kt + 1) << 6;
            pa0 = *(const f16x8*)(arow + k0 + skb);
            pa1 = *(const f16x8*)(arow + k0 + skb + 8);
#pragma unroll
            for (int i = 0; i < 16; ++i) pb[i] = wdp[(size_t)(k0 + skb + i) * HH + n0 + sr];
        }
#pragma unroll
        for (int h = 0; h < 2; ++h) {
            const int kf = (h << 5) + (lg << 3);
            f16x8 af[2], bf[2];
#pragma unroll
            for (int f = 0; f < 2; ++f) {
                af[f] = *(const f16x8*)&As[wm + (f << 4) + lm][kf];
                bf[f] = *(const f16x8*)&Bs[wn + (f << 4) + lm][kf];
            }
#pragma unroll
            for (int fi = 0; fi < 2; ++fi)
#pragma unroll
                for (int fj = 0; fj < 2; ++fj)
                    acc[fi][fj] = __builtin_amdgcn_mfma_f32_16x16x32_f16(af[fi], bf[fj], acc[fi][fj], 0, 0, 0);
        }
        if (more) {
            __syncthreads();
            f16x8 g0, g1;
#pragma unroll
            for (int j = 0; j < 8; ++j) { g0[j] = (f16)pb[j]; g1[j] = (f16)pb[8+j]; }
            *(f16x8*)&As[sr][skb] = pa0; *(f16x8*)&As[sr][skb+8] = pa1;
            *(f16x8*)&Bs[sr][skb] = g0;  *(f16x8*)&Bs[sr][skb+8] = g1;
            __syncthreads();
        }
    }
#pragma unroll
    for (int fi = 0; fi < 2; ++fi)
#pragma unroll
        for (int rr = 0; rr < 4; ++rr) {
            const int m = wm + (fi << 4) + (lg << 2) + rr;
            const int row = r0 + m;
            if (row < cnt) {
                int t; float wt;
                if (e < NE) { t = token_list[e * TT + row]; wt = weight_list[e * TT + row]; }
                else        { t = row; wt = 1.f; }
                float* orow = out + (size_t)t * HH + n0;
#pragma unroll
                for (int fj = 0; fj < 2; ++fj)
                    atomicAdd(&orow[wn + (fj << 4) + lm], wt * acc[fi][fj][rr]);
            }
        }
}

extern "C" void kernel_launch(void* const* d_in, const int* in_sizes, int n_in,
                              void* d_out, int out_size, void* d_ws, size_t ws_size,
                              hipStream_t stream)
{
    const float* x       = (const float*)d_in[0];
    const float* gate_w  = (const float*)d_in[1];
    const float* w_gate  = (const float*)d_in[2];
    const float* w_up    = (const float*)d_in[3];
    const float* w_down  = (const float*)d_in[4];
    const float* ws_gate = (const float*)d_in[5];
    const float* ws_up   = (const float*)d_in[6];
    const float* ws_down = (const float*)d_in[7];
    float* out = (float*)d_out;

    // workspace: counts[16] | offs[17] | pad to 64 ints | token_list[16*1024] |
    // weight_list[16*1024] | rinter f16 [3072][512]
    int* counts = (int*)d_ws;
    int* offs = counts + 16;
    int* token_list = counts + 64;
    float* weight_list = (float*)(counts + 64 + NE * TT);
    f16* rinter = (f16*)(counts + 64 + 2 * NE * TT);

    hipMemsetAsync(counts, 0, 64, stream);
    hipMemsetAsync(out, 0, (size_t)TT * HH * sizeof(float), stream);
    router_k<<<dim3(TT / 4), 256, 0, stream>>>(x, gate_w, counts, token_list, weight_list);
    prefix_k<<<1, 64, 0, stream>>>(counts, offs);
    // grid: x = n-tile (always active -> spreads over all 8 XCDs), y = row-tile, z = expert
    gu_k<<<dim3(MM / 64, TT / 64, NE + 1), 256, 0, stream>>>(
        x, w_gate, w_up, ws_gate, ws_up, counts, offs, token_list, rinter);
    down_k<<<dim3(HH / 64, TT / 64, NE + 1), 256, 0, stream>>>(
        rinter, w_down, ws_down, counts, offs, token_list, weight_list, out);
}

// Round 5
// 122.016 us; speedup vs baseline: 2.1726x; 1.0957x over previous
//
#include <hip/hip_runtime.h>
#include <math.h>

#define TT 1024   // tokens
#define HH 1024   // hidden
#define MM 512    // moe intermediate
#define NE 16     // routed experts (blockIdx.z == NE -> shared expert)
// TOP_K = 2, SCALE = 2.5, NORM_TOPK = true

typedef _Float16 f16;
typedef _Float16 f16x8 __attribute__((ext_vector_type(8)));
typedef float f32x4 __attribute__((ext_vector_type(4)));

// LDS rows padded to 72 f16 (144 B): b128 ops land 8 lanes on each of 8 bank
// groups = the wave64 b128 structural minimum (1KB / 128B-per-cycle).
#define LPAD 72

// ---------------- router ----------------
__global__ __launch_bounds__(256) void router_k(
    const float* __restrict__ x, const float* __restrict__ gate_w,
    int* __restrict__ counts, int* __restrict__ token_list, float* __restrict__ weight_list)
{
    const int wave = threadIdx.x >> 6;
    const int lane = threadIdx.x & 63;
    const int t = (blockIdx.x << 2) + wave;
    const float* xr = x + (size_t)t * HH;
    float xv[16];
#pragma unroll
    for (int i = 0; i < 16; ++i) xv[i] = xr[lane + (i << 6)];
    float sc[NE];
#pragma unroll
    for (int e = 0; e < NE; ++e) {
        const float* gr = gate_w + e * HH;
        float acc = 0.f;
#pragma unroll
        for (int i = 0; i < 16; ++i) acc = fmaf(xv[i], gr[lane + (i << 6)], acc);
#pragma unroll
        for (int off = 32; off > 0; off >>= 1) acc += __shfl_down(acc, off, 64);
        sc[e] = acc;   // valid on lane 0
    }
    if (lane == 0) {
        float l1 = -1e30f, l2 = -1e30f; int i1 = 0, i2 = 0;
#pragma unroll
        for (int e = 0; e < NE; ++e) {
            float v = sc[e];
            if (v > l1) { l2 = l1; i2 = i1; l1 = v; i1 = e; }
            else if (v > l2) { l2 = v; i2 = e; }
        }
        float w1 = 1.f / (1.f + __expf(-l1));
        float w2 = 1.f / (1.f + __expf(-l2));
        const float inv = 2.5f / (w1 + w2 + 1e-20f);
        w1 *= inv; w2 *= inv;
        int s1 = atomicAdd(&counts[i1], 1);
        token_list[i1 * TT + s1] = t;
        weight_list[i1 * TT + s1] = w1;
        int s2 = atomicAdd(&counts[i2], 1);
        token_list[i2 * TT + s2] = t;
        weight_list[i2 * TT + s2] = w2;
    }
}

__global__ void prefix_k(const int* __restrict__ counts, int* __restrict__ offs)
{
    if (threadIdx.x == 0 && blockIdx.x == 0) {
        int acc = 0;
#pragma unroll
        for (int e = 0; e < NE; ++e) { offs[e] = acc; acc += counts[e]; }
        offs[NE] = acc;
    }
}

// ================= fused gate/up =================
// grid = (n_tiles, row_tiles, experts+1). BM=BN=BK=64, 256 thr (4 waves 2x2).
// Depth-2 register pipeline + double-buffered LDS: no vmcnt drain in steady state.

#define GU_LOAD(PA, PG, PU, K0)                                           \
  { _Pragma("unroll") for (int u = 0; u < 4; ++u) {                       \
      float4 v = *(const float4*)(arow + (K0) + skb + (u << 2));          \
      PA[4*u] = v.x; PA[4*u+1] = v.y; PA[4*u+2] = v.z; PA[4*u+3] = v.w; } \
    _Pragma("unroll") for (int i = 0; i < 16; ++i) {                      \
      PG[i] = wgp[(size_t)((K0) + skb + i) * MM + n0 + sr];               \
      PU[i] = wup[(size_t)((K0) + skb + i) * MM + n0 + sr]; } }

#define GU_CW(PA, PG, PU, AS, BGS, BUS)                                   \
  { f16x8 a0, a1, g0, g1, u0, u1;                                         \
    _Pragma("unroll") for (int j = 0; j < 8; ++j) {                       \
      a0[j] = (f16)PA[j]; a1[j] = (f16)PA[8+j];                           \
      g0[j] = (f16)PG[j]; g1[j] = (f16)PG[8+j];                           \
      u0[j] = (f16)PU[j]; u1[j] = (f16)PU[8+j]; }                         \
    *(f16x8*)&AS[sr][skb]  = a0; *(f16x8*)&AS[sr][skb+8]  = a1;           \
    *(f16x8*)&BGS[sr][skb] = g0; *(f16x8*)&BGS[sr][skb+8] = g1;           \
    *(f16x8*)&BUS[sr][skb] = u0; *(f16x8*)&BUS[sr][skb+8] = u1; }

#define GU_COMP(AS, BGS, BUS)                                             \
  { _Pragma("unroll") for (int h = 0; h < 2; ++h) {                       \
      const int kf = (h << 5) + (lg << 3);                                \
      f16x8 af[2], bgf[2], buf2[2];                                       \
      _Pragma("unroll") for (int f = 0; f < 2; ++f) {                     \
        af[f]   = *(const f16x8*)&AS[wm + (f << 4) + lm][kf];             \
        bgf[f]  = *(const f16x8*)&BGS[wn + (f << 4) + lm][kf];            \
        buf2[f] = *(const f16x8*)&BUS[wn + (f << 4) + lm][kf]; }          \
      _Pragma("unroll") for (int fi = 0; fi < 2; ++fi)                    \
        _Pragma("unroll") for (int fj = 0; fj < 2; ++fj) {                \
          accg[fi][fj] = __builtin_amdgcn_mfma_f32_16x16x32_f16(af[fi], bgf[fj], accg[fi][fj], 0, 0, 0); \
          accu[fi][fj] = __builtin_amdgcn_mfma_f32_16x16x32_f16(af[fi], buf2[fj], accu[fi][fj], 0, 0, 0); } } }

__global__ __launch_bounds__(256, 2) void gu_k(
    const float* __restrict__ x,
    const float* __restrict__ w_gate, const float* __restrict__ w_up,
    const float* __restrict__ ws_gate, const float* __restrict__ ws_up,
    const int* __restrict__ counts, const int* __restrict__ offs,
    const int* __restrict__ token_list, f16* __restrict__ rinter)
{
    const int e = blockIdx.z;
    int cnt, slot0;
    const float *wgp, *wup;
    if (e < NE) {
        cnt = counts[e]; slot0 = offs[e];
        wgp = w_gate + (size_t)e * HH * MM;
        wup = w_up   + (size_t)e * HH * MM;
    } else {
        cnt = TT; slot0 = 2 * TT;
        wgp = ws_gate; wup = ws_up;
    }
    const int r0 = blockIdx.y << 6;
    if (r0 >= cnt) return;
    const int n0 = blockIdx.x << 6;

    __shared__ f16 As0[64][LPAD], Bgs0[64][LPAD], Bus0[64][LPAD];
    __shared__ f16 As1[64][LPAD], Bgs1[64][LPAD], Bus1[64][LPAD];
    __shared__ int toks[64];

    const int tid = threadIdx.x;
    if (tid < 64) {
        int i = r0 + tid; if (i >= cnt) i = cnt - 1;
        toks[tid] = (e < NE) ? token_list[e * TT + i] : i;
    }
    __syncthreads();

    const int sr  = tid & 63;
    const int skb = (tid >> 6) << 4;
    const int w = tid >> 6, l = tid & 63;
    const int wm = (w >> 1) << 5, wn = (w & 1) << 5;
    const int lm = l & 15, lg = l >> 4;

    const float* arow = x + (size_t)toks[sr] * HH;

    f32x4 accg[2][2] = {}, accu[2][2] = {};
    float pa0v[16], pg0v[16], pu0v[16];
    float pa1v[16], pg1v[16], pu1v[16];

    // prologue: tiles 0,1 in flight; tile0 -> LDS0
    GU_LOAD(pa0v, pg0v, pu0v, 0)
    GU_LOAD(pa1v, pg1v, pu1v, 64)
    GU_CW(pa0v, pg0v, pu0v, As0, Bgs0, Bus0)   // counted wait (tile1 stays in flight)
    __syncthreads();

#pragma unroll 1
    for (int kt = 0; kt < HH / 64; kt += 2) {
        // phase A: prefetch kt+2 -> set0; stage kt+1 (set1) -> LDS1; compute kt from LDS0
        if (kt + 2 < HH / 64) GU_LOAD(pa0v, pg0v, pu0v, (kt + 2) << 6)
        GU_CW(pa1v, pg1v, pu1v, As1, Bgs1, Bus1)
        GU_COMP(As0, Bgs0, Bus0)
        __syncthreads();
        // phase B: prefetch kt+3 -> set1; stage kt+2 (set0) -> LDS0; compute kt+1 from LDS1
        if (kt + 3 < HH / 64) GU_LOAD(pa1v, pg1v, pu1v, (kt + 3) << 6)
        if (kt + 2 < HH / 64) GU_CW(pa0v, pg0v, pu0v, As0, Bgs0, Bus0)
        GU_COMP(As1, Bgs1, Bus1)
        __syncthreads();
    }
    // epilogue: silu(g)*u -> f16; C/D: col=lane&15, row=(lane>>4)*4+reg
#pragma unroll
    for (int fi = 0; fi < 2; ++fi)
#pragma unroll
        for (int rr = 0; rr < 4; ++rr) {
            const int m = wm + (fi << 4) + (lg << 2) + rr;
            if (r0 + m < cnt) {
                f16* orow = rinter + (size_t)(slot0 + r0 + m) * MM + n0;
#pragma unroll
                for (int fj = 0; fj < 2; ++fj) {
                    float g = accg[fi][fj][rr], u = accu[fi][fj][rr];
                    float s = g / (1.f + __expf(-g));
                    orow[wn + (fj << 4) + lm] = (f16)(s * u);
                }
            }
        }
}

// ================= down: out[token] += weight * (rinter @ Wd) =================

#define DN_LOAD(PA0, PA1, PB, K0)                                         \
  { PA0 = *(const f16x8*)(arow + (K0) + skb);                             \
    PA1 = *(const f16x8*)(arow + (K0) + skb + 8);                         \
    _Pragma("unroll") for (int i = 0; i < 16; ++i)                        \
      PB[i] = wdp[(size_t)((K0) + skb + i) * HH + n0 + sr]; }

#define DN_CW(PA0, PA1, PB, AS, BS)                                       \
  { f16x8 g0, g1;                                                         \
    _Pragma("unroll") for (int j = 0; j < 8; ++j) {                       \
      g0[j] = (f16)PB[j]; g1[j] = (f16)PB[8+j]; }                         \
    *(f16x8*)&AS[sr][skb] = PA0; *(f16x8*)&AS[sr][skb+8] = PA1;           \
    *(f16x8*)&BS[sr][skb] = g0;  *(f16x8*)&BS[sr][skb+8] = g1; }

#define DN_COMP(AS, BS)                                                   \
  { _Pragma("unroll") for (int h = 0; h < 2; ++h) {                       \
      const int kf = (h << 5) + (lg << 3);                                \
      f16x8 af[2], bf[2];                                                 \
      _Pragma("unroll") for (int f = 0; f < 2; ++f) {                     \
        af[f] = *(const f16x8*)&AS[wm + (f << 4) + lm][kf];               \
        bf[f] = *(const f16x8*)&BS[wn + (f << 4) + lm][kf]; }             \
      _Pragma("unroll") for (int fi = 0; fi < 2; ++fi)                    \
        _Pragma("unroll") for (int fj = 0; fj < 2; ++fj)                  \
          acc[fi][fj] = __builtin_amdgcn_mfma_f32_16x16x32_f16(af[fi], bf[fj], acc[fi][fj], 0, 0, 0); } }

__global__ __launch_bounds__(256, 2) void down_k(
    const f16* __restrict__ rinter,
    const float* __restrict__ w_down, const float* __restrict__ ws_down,
    const int* __restrict__ counts, const int* __restrict__ offs,
    const int* __restrict__ token_list, const float* __restrict__ weight_list,
    float* __restrict__ out)
{
    const int e = blockIdx.z;
    int cnt, slot0; const float* wdp;
    if (e < NE) { cnt = counts[e]; slot0 = offs[e]; wdp = w_down + (size_t)e * MM * HH; }
    else        { cnt = TT; slot0 = 2 * TT; wdp = ws_down; }
    const int r0 = blockIdx.y << 6;
    if (r0 >= cnt) return;
    const int n0 = blockIdx.x << 6;   // of HH

    __shared__ f16 As0[64][LPAD], Bs0[64][LPAD];
    __shared__ f16 As1[64][LPAD], Bs1[64][LPAD];

    const int tid = threadIdx.x;
    const int sr  = tid & 63;
    const int skb = (tid >> 6) << 4;
    const int w = tid >> 6, l = tid & 63;
    const int wm = (w >> 1) << 5, wn = (w & 1) << 5;
    const int lm = l & 15, lg = l >> 4;

    int ari = r0 + sr; if (ari >= cnt) ari = cnt - 1;
    const f16* arow = rinter + (size_t)(slot0 + ari) * MM;

    f32x4 acc[2][2] = {};
    f16x8 pa00, pa01, pa10, pa11; float pb0[16], pb1[16];

    DN_LOAD(pa00, pa01, pb0, 0)
    DN_LOAD(pa10, pa11, pb1, 64)
    DN_CW(pa00, pa01, pb0, As0, Bs0)
    __syncthreads();

#pragma unroll 1
    for (int kt = 0; kt < MM / 64; kt += 2) {
        if (kt + 2 < MM / 64) DN_LOAD(pa00, pa01, pb0, (kt + 2) << 6)
        DN_CW(pa10, pa11, pb1, As1, Bs1)
        DN_COMP(As0, Bs0)
        __syncthreads();
        if (kt + 3 < MM / 64) DN_LOAD(pa10, pa11, pb1, (kt + 3) << 6)
        if (kt + 2 < MM / 64) DN_CW(pa00, pa01, pb0, As0, Bs0)
        DN_COMP(As1, Bs1)
        __syncthreads();
    }
#pragma unroll
    for (int fi = 0; fi < 2; ++fi)
#pragma unroll
        for (int rr = 0; rr < 4; ++rr) {
            const int m = wm + (fi << 4) + (lg << 2) + rr;
            const int row = r0 + m;
            if (row < cnt) {
                int t; float wt;
                if (e < NE) { t = token_list[e * TT + row]; wt = weight_list[e * TT + row]; }
                else        { t = row; wt = 1.f; }
                float* orow = out + (size_t)t * HH + n0;
#pragma unroll
                for (int fj = 0; fj < 2; ++fj)
                    atomicAdd(&orow[wn + (fj << 4) + lm], wt * acc[fi][fj][rr]);
            }
        }
}

extern "C" void kernel_launch(void* const* d_in, const int* in_sizes, int n_in,
                              void* d_out, int out_size, void* d_ws, size_t ws_size,
                              hipStream_t stream)
{
    const float* x       = (const float*)d_in[0];
    const float* gate_w  = (const float*)d_in[1];
    const float* w_gate  = (const float*)d_in[2];
    const float* w_up    = (const float*)d_in[3];
    const float* w_down  = (const float*)d_in[4];
    const float* ws_gate = (const float*)d_in[5];
    const float* ws_up   = (const float*)d_in[6];
    const float* ws_down = (const float*)d_in[7];
    float* out = (float*)d_out;

    // workspace: counts[16] | offs[17] | pad to 64 ints | token_list[16*1024] |
    // weight_list[16*1024] | rinter f16 [3072][512]
    int* counts = (int*)d_ws;
    int* offs = counts + 16;
    int* token_list = counts + 64;
    float* weight_list = (float*)(counts + 64 + NE * TT);
    f16* rinter = (f16*)(counts + 64 + 2 * NE * TT);

    hipMemsetAsync(counts, 0, 64, stream);
    hipMemsetAsync(out, 0, (size_t)TT * HH * sizeof(float), stream);
    router_k<<<dim3(TT / 4), 256, 0, stream>>>(x, gate_w, counts, token_list, weight_list);
    prefix_k<<<1, 64, 0, stream>>>(counts, offs);
    // grid: x = n-tile (always active -> spreads over all 8 XCDs), y = row-tile, z = expert
    gu_k<<<dim3(MM / 64, TT / 64, NE + 1), 256, 0, stream>>>(
        x, w_gate, w_up, ws_gate, ws_up, counts, offs, token_list, rinter);
    down_k<<<dim3(HH / 64, TT / 64, NE + 1), 256, 0, stream>>>(
        rinter, w_down, ws_down, counts, offs, token_list, weight_list, out);
}